// Round 1
// baseline (1867.302 us; speedup 1.0000x reference)
//
#include <hip/hip_runtime.h>
#include <cstdint>
#include <cstddef>

#define NODES  100000
#define EDGES  3200000
#define FIN    128
#define HIDDEN 256
#define EMBD   128
#define GRAPHS 2048

// ---------------- CSR build ----------------
__global__ void hist_k(const int* __restrict__ dst, int* __restrict__ cnt) {
  int stride = gridDim.x * blockDim.x;
  for (int i = blockIdx.x * blockDim.x + threadIdx.x; i < EDGES; i += stride)
    atomicAdd(&cnt[dst[i]], 1);
}

__global__ void scan1_k(const int* __restrict__ cnt, int* __restrict__ row_ptr,
                        int* __restrict__ bsum) {
  __shared__ int sh[256];
  int i = blockIdx.x * 256 + threadIdx.x;
  int v = (i < NODES) ? cnt[i] : 0;
  sh[threadIdx.x] = v;
  __syncthreads();
  for (int off = 1; off < 256; off <<= 1) {
    int t = (threadIdx.x >= off) ? sh[threadIdx.x - off] : 0;
    __syncthreads();
    sh[threadIdx.x] += t;
    __syncthreads();
  }
  if (i < NODES) row_ptr[i + 1] = sh[threadIdx.x];
  if (threadIdx.x == 255) bsum[blockIdx.x] = sh[255];
}

__global__ void scan2_k(int* __restrict__ bsum, int nb) {
  __shared__ int sh[512];
  int v = (threadIdx.x < nb) ? bsum[threadIdx.x] : 0;
  sh[threadIdx.x] = v;
  __syncthreads();
  for (int off = 1; off < 512; off <<= 1) {
    int t = (threadIdx.x >= off) ? sh[threadIdx.x - off] : 0;
    __syncthreads();
    sh[threadIdx.x] += t;
    __syncthreads();
  }
  if (threadIdx.x < nb) bsum[threadIdx.x] = sh[threadIdx.x] - v;  // exclusive
}

__global__ void scan3_k(const int* __restrict__ cnt, const int* __restrict__ bsum,
                        int* __restrict__ row_ptr, float* __restrict__ dinv,
                        int* __restrict__ cursor) {
  int i = blockIdx.x * 256 + threadIdx.x;
  if (i >= NODES) return;
  row_ptr[i + 1] += bsum[blockIdx.x];
  dinv[i] = rsqrtf((float)(cnt[i] + 1));
  cursor[i] = 0;
  if (i == 0) row_ptr[0] = 0;
}

__global__ void fill_k(const int* __restrict__ src, const int* __restrict__ dst,
                       const int* __restrict__ row_ptr, int* __restrict__ cursor,
                       int* __restrict__ csr_src) {
  int stride = gridDim.x * blockDim.x;
  for (int i = blockIdx.x * blockDim.x + threadIdx.x; i < EDGES; i += stride) {
    int d = dst[i];
    int pos = row_ptr[d] + atomicAdd(&cursor[d], 1);
    csr_src[pos] = src[i];
  }
}

// ---------------- aggregation: out[i] = dinv[i]*sum_{s in N(i)} dinv[s]*in[s] + dinv[i]^2*in[i] (+bias)
template <int D>
__global__ void agg_k(const float* __restrict__ in, float* __restrict__ out,
                      const int* __restrict__ row_ptr, const int* __restrict__ csr_src,
                      const float* __restrict__ dinv, const float* __restrict__ bias) {
  constexpr int V = D / 64;  // floats per lane (2 for 128, 4 for 256)
  int node = (blockIdx.x * blockDim.x + threadIdx.x) >> 6;
  int lane = threadIdx.x & 63;
  if (node >= NODES) return;
  const int c0 = lane * V;

  float acc[V];
#pragma unroll
  for (int v = 0; v < V; ++v) acc[v] = 0.f;

  int beg = row_ptr[node], end = row_ptr[node + 1];
  for (int k = beg; k < end; ++k) {
    int s = csr_src[k];
    float w = dinv[s];
    const float* rp = in + (size_t)s * D + c0;
    if (V == 4) {
      float4 xv = *(const float4*)rp;
      acc[0] = fmaf(w, xv.x, acc[0]);
      acc[1] = fmaf(w, xv.y, acc[1]);
      acc[2] = fmaf(w, xv.z, acc[2]);
      acc[3] = fmaf(w, xv.w, acc[3]);
    } else {
      float2 xv = *(const float2*)rp;
      acc[0] = fmaf(w, xv.x, acc[0]);
      acc[1] = fmaf(w, xv.y, acc[1]);
    }
  }

  float di = dinv[node];
  float dii = di * di;
  const float* sp = in + (size_t)node * D + c0;
  float* op = out + (size_t)node * D + c0;

  if (V == 4) {
    float4 sv = *(const float4*)sp;
    float4 o;
    o.x = di * acc[0] + dii * sv.x;
    o.y = di * acc[1] + dii * sv.y;
    o.z = di * acc[2] + dii * sv.z;
    o.w = di * acc[3] + dii * sv.w;
    if (bias) { o.x += bias[c0]; o.y += bias[c0 + 1]; o.z += bias[c0 + 2]; o.w += bias[c0 + 3]; }
    *(float4*)op = o;
  } else {
    float2 sv = *(const float2*)sp;
    float2 o;
    o.x = di * acc[0] + dii * sv.x;
    o.y = di * acc[1] + dii * sv.y;
    if (bias) { o.x += bias[c0]; o.y += bias[c0 + 1]; }
    *(float2*)op = o;
  }
}

// ---------------- fp32 GEMM: C[N,M] = act(A[N,K] @ W[K,M] + bias)
// 128x128 tile, KB=16, 256 threads, 8x8 micro-tile (split 4+4 with +64 offset to keep
// LDS reads <=2-way bank aliased).
template <int K, bool RELU, bool HAS_BIAS>
__global__ __launch_bounds__(256) void gemm_k(const float* __restrict__ A,
                                              const float* __restrict__ W,
                                              const float* __restrict__ bias,
                                              float* __restrict__ C, int N, int M) {
  constexpr int KB = 16;
  __shared__ float As[KB][128];  // [k][row]
  __shared__ float Ws[KB][128];  // [k][col]

  const int tid = threadIdx.x;
  const int rowbase = blockIdx.x * 128;
  const int colbase = blockIdx.y * 128;
  const int tr = tid >> 4;  // 0..15
  const int tc = tid & 15;  // 0..15

  // A-load mapping: thread covers row ar, two float4 k-chunks
  const int ar = tid >> 1;
  const int ac4_0 = (tid & 1) * 2;
  // W-load mapping
  const int wk = tid >> 4;
  const int wc4_0 = (tid & 15) * 2;

  float acc[8][8];
#pragma unroll
  for (int i = 0; i < 8; ++i)
#pragma unroll
    for (int j = 0; j < 8; ++j) acc[i][j] = 0.f;

  for (int kb = 0; kb < K; kb += KB) {
#pragma unroll
    for (int q = 0; q < 2; ++q) {
      int c4 = ac4_0 + q;
      int grow = rowbase + ar;
      float4 v = make_float4(0.f, 0.f, 0.f, 0.f);
      if (grow < N) v = *(const float4*)(A + (size_t)grow * K + kb + c4 * 4);
      As[c4 * 4 + 0][ar] = v.x;
      As[c4 * 4 + 1][ar] = v.y;
      As[c4 * 4 + 2][ar] = v.z;
      As[c4 * 4 + 3][ar] = v.w;
    }
#pragma unroll
    for (int q = 0; q < 2; ++q) {
      int c4 = wc4_0 + q;
      float4 v = *(const float4*)(W + (size_t)(kb + wk) * M + colbase + c4 * 4);
      *(float4*)&Ws[wk][c4 * 4] = v;
    }
    __syncthreads();

#pragma unroll
    for (int kk = 0; kk < KB; ++kk) {
      float4 a0 = *(const float4*)&As[kk][tr * 4];
      float4 a1 = *(const float4*)&As[kk][tr * 4 + 64];
      float4 w0 = *(const float4*)&Ws[kk][tc * 4];
      float4 w1 = *(const float4*)&Ws[kk][tc * 4 + 64];
      float a[8] = {a0.x, a0.y, a0.z, a0.w, a1.x, a1.y, a1.z, a1.w};
      float w[8] = {w0.x, w0.y, w0.z, w0.w, w1.x, w1.y, w1.z, w1.w};
#pragma unroll
      for (int i = 0; i < 8; ++i)
#pragma unroll
        for (int j = 0; j < 8; ++j) acc[i][j] = fmaf(a[i], w[j], acc[i][j]);
    }
    __syncthreads();
  }

#pragma unroll
  for (int i = 0; i < 8; ++i) {
    int r = rowbase + ((i < 4) ? (tr * 4 + i) : (64 + tr * 4 + (i - 4)));
    if (r >= N) continue;
#pragma unroll
    for (int jh = 0; jh < 2; ++jh) {
      int c = colbase + tc * 4 + jh * 64;
      float4 o;
      o.x = acc[i][jh * 4 + 0];
      o.y = acc[i][jh * 4 + 1];
      o.z = acc[i][jh * 4 + 2];
      o.w = acc[i][jh * 4 + 3];
      if (HAS_BIAS) {
        o.x += bias[c]; o.y += bias[c + 1]; o.z += bias[c + 2]; o.w += bias[c + 3];
      }
      if (RELU) {
        o.x = fmaxf(o.x, 0.f); o.y = fmaxf(o.y, 0.f);
        o.z = fmaxf(o.z, 0.f); o.w = fmaxf(o.w, 0.f);
      }
      *(float4*)(C + (size_t)r * M + c) = o;
    }
  }
}

// ---------------- mean pooling per graph (batch sorted) ----------------
__global__ void pool_k(const float* __restrict__ h, const int* __restrict__ batch,
                       float* __restrict__ pooled) {
  int g = blockIdx.x;
  int j = threadIdx.x;  // 128 threads = EMBD
  int lo = 0, hi = NODES;
  while (lo < hi) { int mid = (lo + hi) >> 1; if (batch[mid] < g) lo = mid + 1; else hi = mid; }
  int start = lo;
  int lo2 = start, hi2 = NODES;
  while (lo2 < hi2) { int mid = (lo2 + hi2) >> 1; if (batch[mid] < g + 1) lo2 = mid + 1; else hi2 = mid; }
  int end = lo2;
  float s = 0.f;
  for (int r = start; r < end; ++r) s += h[(size_t)r * EMBD + j];
  float c = (float)(end - start);
  pooled[g * EMBD + j] = s / fmaxf(c, 1.f);
}

// ---------------- head: logits = z2 @ Wc3[128,2] + bc3 ----------------
__global__ void head_k(const float* __restrict__ z2, const float* __restrict__ Wc3,
                       const float* __restrict__ bc3, float* __restrict__ out) {
  int wv = (blockIdx.x * blockDim.x + threadIdx.x) >> 6;
  int lane = threadIdx.x & 63;
  if (wv >= GRAPHS) return;
  float2 z = *(const float2*)(z2 + (size_t)wv * 128 + lane * 2);
  int j0 = lane * 2;
  float a0 = z.x * Wc3[j0 * 2 + 0] + z.y * Wc3[(j0 + 1) * 2 + 0];
  float a1 = z.x * Wc3[j0 * 2 + 1] + z.y * Wc3[(j0 + 1) * 2 + 1];
  for (int off = 32; off; off >>= 1) {
    a0 += __shfl_down(a0, off);
    a1 += __shfl_down(a1, off);
  }
  if (lane == 0) {
    out[wv * 2 + 0] = a0 + bc3[0];
    out[wv * 2 + 1] = a1 + bc3[1];
  }
}

extern "C" void kernel_launch(void* const* d_in, const int* in_sizes, int n_in,
                              void* d_out, int out_size, void* d_ws, size_t ws_size,
                              hipStream_t stream) {
  const float* x    = (const float*)d_in[0];
  const int*   ei   = (const int*)d_in[1];
  const int*   batch= (const int*)d_in[2];
  const float* W1 = (const float*)d_in[3];  const float* b1 = (const float*)d_in[4];
  const float* W2 = (const float*)d_in[5];  const float* b2 = (const float*)d_in[6];
  const float* W3 = (const float*)d_in[7];  const float* b3 = (const float*)d_in[8];
  const float* Wc1= (const float*)d_in[9];  const float* bc1= (const float*)d_in[10];
  const float* Wc2= (const float*)d_in[11]; const float* bc2= (const float*)d_in[12];
  const float* Wc3= (const float*)d_in[13]; const float* bc3= (const float*)d_in[14];
  float* out = (float*)d_out;

  char* ws = (char*)d_ws;
  size_t off = 0;
  auto alloc = [&](size_t bytes) -> void* {
    void* p = ws + off;
    off = (off + bytes + 255) & ~(size_t)255;
    return p;
  };
  float* R0      = (float*)alloc((size_t)NODES * 256 * 4);
  float* R1      = (float*)alloc((size_t)NODES * 256 * 4);
  int*   csr_src = (int*)alloc((size_t)EDGES * 4);
  int*   row_ptr = (int*)alloc((size_t)(NODES + 1) * 4);
  int*   cnt     = (int*)alloc((size_t)NODES * 4);
  int*   cursor  = (int*)alloc((size_t)NODES * 4);
  float* dinv    = (float*)alloc((size_t)NODES * 4);
  int*   bsum    = (int*)alloc(512 * 4);
  // overlays in R0 (dead by pooling time)
  float* pooled = R0;
  float* z1     = R0 + (size_t)GRAPHS * EMBD;
  float* z2     = z1 + (size_t)GRAPHS * HIDDEN;

  const int* srcA = ei;
  const int* dstA = ei + EDGES;

  const int nb = (NODES + 255) / 256;  // 391
  hipMemsetAsync(cnt, 0, (size_t)NODES * 4, stream);
  hist_k<<<2048, 256, 0, stream>>>(dstA, cnt);
  scan1_k<<<nb, 256, 0, stream>>>(cnt, row_ptr, bsum);
  scan2_k<<<1, 512, 0, stream>>>(bsum, nb);
  scan3_k<<<nb, 256, 0, stream>>>(cnt, bsum, row_ptr, dinv, cursor);
  fill_k<<<2048, 256, 0, stream>>>(srcA, dstA, row_ptr, cursor, csr_src);

  const int aggBlocks = (NODES * 64 + 255) / 256;  // 25000
  const int gemmRows = (NODES + 127) / 128;        // 782

  // L1: AX = agg(x) [128]; H1 = relu(AX@W1 + b1) [256]
  agg_k<128><<<aggBlocks, 256, 0, stream>>>(x, R0, row_ptr, csr_src, dinv, nullptr);
  gemm_k<128, true, true><<<dim3(gemmRows, 2), 256, 0, stream>>>(R0, W1, b1, R1, NODES, HIDDEN);
  // L2: AH1 = agg(H1) [256]; H2 = relu(AH1@W2 + b2) [256]
  agg_k<256><<<aggBlocks, 256, 0, stream>>>(R1, R0, row_ptr, csr_src, dinv, nullptr);
  gemm_k<256, true, true><<<dim3(gemmRows, 2), 256, 0, stream>>>(R0, W2, b2, R1, NODES, HIDDEN);
  // L3: G3 = H2@W3 [128]; H3 = agg(G3) + b3 [128]
  gemm_k<256, false, false><<<dim3(gemmRows, 1), 256, 0, stream>>>(R1, W3, nullptr, R0, NODES, EMBD);
  agg_k<128><<<aggBlocks, 256, 0, stream>>>(R0, R1, row_ptr, csr_src, dinv, b3);
  // pooling + MLP head
  pool_k<<<GRAPHS, 128, 0, stream>>>(R1, batch, pooled);
  gemm_k<128, true, true><<<dim3((GRAPHS + 127) / 128, 2), 256, 0, stream>>>(pooled, Wc1, bc1, z1, GRAPHS, HIDDEN);
  gemm_k<256, true, true><<<dim3((GRAPHS + 127) / 128, 1), 256, 0, stream>>>(z1, Wc2, bc2, z2, GRAPHS, EMBD);
  head_k<<<GRAPHS / 4, 256, 0, stream>>>(z2, Wc3, bc3, out);
}

// Round 2
// 1398.220 us; speedup vs baseline: 1.3355x; 1.3355x over previous
//
#include <hip/hip_runtime.h>
#include <cstdint>
#include <cstddef>

#define NODES  100000
#define EDGES  3200000
#define FIN    128
#define HIDDEN 256
#define EMBD   128
#define GRAPHS 2048

typedef _Float16 f16;
typedef f16 f16x2 __attribute__((ext_vector_type(2)));
typedef f16 f16x4 __attribute__((ext_vector_type(4)));
typedef f16 f16x8 __attribute__((ext_vector_type(8)));
typedef float f32x4 __attribute__((ext_vector_type(4)));

// ---------------- CSR build ----------------
__global__ void hist_k(const int* __restrict__ dst, int* __restrict__ cnt) {
  int stride = gridDim.x * blockDim.x;
  for (int i = blockIdx.x * blockDim.x + threadIdx.x; i < EDGES; i += stride)
    atomicAdd(&cnt[dst[i]], 1);
}

__global__ void scan1_k(const int* __restrict__ cnt, int* __restrict__ row_ptr,
                        int* __restrict__ bsum) {
  __shared__ int sh[256];
  int i = blockIdx.x * 256 + threadIdx.x;
  int v = (i < NODES) ? cnt[i] : 0;
  sh[threadIdx.x] = v;
  __syncthreads();
  for (int off = 1; off < 256; off <<= 1) {
    int t = (threadIdx.x >= off) ? sh[threadIdx.x - off] : 0;
    __syncthreads();
    sh[threadIdx.x] += t;
    __syncthreads();
  }
  if (i < NODES) row_ptr[i + 1] = sh[threadIdx.x];
  if (threadIdx.x == 255) bsum[blockIdx.x] = sh[255];
}

__global__ void scan2_k(int* __restrict__ bsum, int nb) {
  __shared__ int sh[512];
  int v = (threadIdx.x < nb) ? bsum[threadIdx.x] : 0;
  sh[threadIdx.x] = v;
  __syncthreads();
  for (int off = 1; off < 512; off <<= 1) {
    int t = (threadIdx.x >= off) ? sh[threadIdx.x - off] : 0;
    __syncthreads();
    sh[threadIdx.x] += t;
    __syncthreads();
  }
  if (threadIdx.x < nb) bsum[threadIdx.x] = sh[threadIdx.x] - v;  // exclusive
}

__global__ void scan3_k(const int* __restrict__ cnt, const int* __restrict__ bsum,
                        int* __restrict__ row_ptr, float* __restrict__ dinv,
                        int* __restrict__ cursor) {
  int i = blockIdx.x * 256 + threadIdx.x;
  if (i >= NODES) return;
  row_ptr[i + 1] += bsum[blockIdx.x];
  dinv[i] = rsqrtf((float)(cnt[i] + 1));
  cursor[i] = 0;
  if (i == 0) row_ptr[0] = 0;
}

__global__ void fill_k(const int* __restrict__ src, const int* __restrict__ dst,
                       const int* __restrict__ row_ptr, int* __restrict__ cursor,
                       int* __restrict__ csr_src) {
  int stride = gridDim.x * blockDim.x;
  for (int i = blockIdx.x * blockDim.x + threadIdx.x; i < EDGES; i += stride) {
    int d = dst[i];
    int pos = row_ptr[d] + atomicAdd(&cursor[d], 1);
    csr_src[pos] = src[i];
  }
}

// ---------------- prescale: xs[i] = f16(dinv[i] * x[i]) ----------------
__global__ void prescale_k(const float* __restrict__ x, const float* __restrict__ dinv,
                           f16* __restrict__ xs) {
  int idx = blockIdx.x * blockDim.x + threadIdx.x;  // over NODES*FIN/4
  if (idx >= NODES * FIN / 4) return;
  int row = idx >> 5;  // FIN/4 = 32 float4 per row
  float4 v = *(const float4*)(x + (size_t)idx * 4);
  float d = dinv[row];
  f16x4 o = {(f16)(d * v.x), (f16)(d * v.y), (f16)(d * v.z), (f16)(d * v.w)};
  *(f16x4*)(xs + (size_t)idx * 4) = o;
}

// ---------------- weight convert+transpose: Wt[m][k] = f16(W[k][m]) ----------------
__global__ void convw_k(const float* __restrict__ W, f16* __restrict__ Wt, int K, int M) {
  int i = blockIdx.x * blockDim.x + threadIdx.x;
  if (i >= K * M) return;
  int k = i / M, m = i - k * M;
  Wt[(size_t)m * K + k] = (f16)W[i];
}

// ---------------- aggregation (f16 in, fp32 accum) ----------------
// in is dinv-prescaled: out[i] = dinv[i] * (sum_{s in N(i)} in[s] + in[i]) (+bias, FINAL->fp32)
template <int V, bool FINAL>
__global__ void agg_h(const f16* __restrict__ in, void* __restrict__ outv,
                      const int* __restrict__ row_ptr, const int* __restrict__ csr_src,
                      const float* __restrict__ dinv, const float* __restrict__ bias) {
  constexpr int D = V * 64;
  int node = (blockIdx.x * blockDim.x + threadIdx.x) >> 6;
  int lane = threadIdx.x & 63;
  if (node >= NODES) return;
  const int c0 = lane * V;

  float acc[V];
#pragma unroll
  for (int v = 0; v < V; ++v) acc[v] = 0.f;

  int beg = row_ptr[node], end = row_ptr[node + 1];
  for (int k = beg; k < end; ++k) {
    int s = csr_src[k];
    if (V == 4) {
      f16x4 hv = *(const f16x4*)(in + (size_t)s * D + c0);
      acc[0] += (float)hv[0]; acc[1] += (float)hv[1];
      acc[2] += (float)hv[2]; acc[3] += (float)hv[3];
    } else {
      f16x2 hv = *(const f16x2*)(in + (size_t)s * D + c0);
      acc[0] += (float)hv[0]; acc[1] += (float)hv[1];
    }
  }
  // self-loop term
  if (V == 4) {
    f16x4 hv = *(const f16x4*)(in + (size_t)node * D + c0);
    acc[0] += (float)hv[0]; acc[1] += (float)hv[1];
    acc[2] += (float)hv[2]; acc[3] += (float)hv[3];
  } else {
    f16x2 hv = *(const f16x2*)(in + (size_t)node * D + c0);
    acc[0] += (float)hv[0]; acc[1] += (float)hv[1];
  }

  float di = dinv[node];
  if (FINAL) {
    float* out = (float*)outv;
    if (V == 4) {
      float4 o = {di * acc[0] + bias[c0], di * acc[1] + bias[c0 + 1],
                  di * acc[2] + bias[c0 + 2], di * acc[3] + bias[c0 + 3]};
      *(float4*)(out + (size_t)node * D + c0) = o;
    } else {
      float2 o = {di * acc[0] + bias[c0], di * acc[1] + bias[c0 + 1]};
      *(float2*)(out + (size_t)node * D + c0) = o;
    }
  } else {
    f16* out = (f16*)outv;
    if (V == 4) {
      f16x4 o = {(f16)(di * acc[0]), (f16)(di * acc[1]),
                 (f16)(di * acc[2]), (f16)(di * acc[3])};
      *(f16x4*)(out + (size_t)node * D + c0) = o;
    } else {
      f16x2 o = {(f16)(di * acc[0]), (f16)(di * acc[1])};
      *(f16x2*)(out + (size_t)node * D + c0) = o;
    }
  }
}

// ---------------- f16 MFMA GEMM: C[N,M] = epi(A[N,K] @ W[K,M]) ----------------
// Wt is W transposed: Wt[m][k]. 128x128 tile, BK=32, 256 thr = 4 waves, each wave 64x64
// via 4x4 fragments of mfma_f32_16x16x32_f16. Epilogue: +bias, relu, *dinv[row], f16 out.
template <int K, bool RELU, bool BIAS, bool DSCALE>
__global__ __launch_bounds__(256) void gemm_h(const f16* __restrict__ A,
                                              const f16* __restrict__ Wt,
                                              const float* __restrict__ bias,
                                              const float* __restrict__ dinv,
                                              f16* __restrict__ C, int N, int M) {
  __shared__ f16 As[128][40];  // [row][k], pad to 40 halves (80B) for bank spread
  __shared__ f16 Bs[128][40];  // [col][k]

  const int tid = threadIdx.x;
  const int rowbase = blockIdx.x * 128;
  const int colbase = blockIdx.y * 128;
  const int l = tid & 63;
  const int wr = ((tid >> 6) >> 1) * 64;  // wave row offset 0/64
  const int wc = ((tid >> 6) & 1) * 64;   // wave col offset 0/64
  const int lr = tid >> 1;                // 0..127: tile row (A) / tile col (B)
  const int lc = (tid & 1) * 16;          // half-offset within BK=32

  f32x4 acc[4][4];
#pragma unroll
  for (int i = 0; i < 4; ++i)
#pragma unroll
    for (int j = 0; j < 4; ++j) acc[i][j] = (f32x4){0.f, 0.f, 0.f, 0.f};

  const int arow = min(rowbase + lr, N - 1);  // clamp: OOB rows read row N-1, never stored
  const f16* aptr = A + (size_t)arow * K + lc;
  const f16* bptr = Wt + (size_t)(colbase + lr) * K + lc;

  for (int kb = 0; kb < K; kb += 32) {
    *(f16x8*)&As[lr][lc]     = *(const f16x8*)(aptr + kb);
    *(f16x8*)&As[lr][lc + 8] = *(const f16x8*)(aptr + kb + 8);
    *(f16x8*)&Bs[lr][lc]     = *(const f16x8*)(bptr + kb);
    *(f16x8*)&Bs[lr][lc + 8] = *(const f16x8*)(bptr + kb + 8);
    __syncthreads();

    f16x8 a[4], b[4];
#pragma unroll
    for (int f = 0; f < 4; ++f) {
      a[f] = *(const f16x8*)&As[wr + f * 16 + (l & 15)][(l >> 4) * 8];
      b[f] = *(const f16x8*)&Bs[wc + f * 16 + (l & 15)][(l >> 4) * 8];
    }
#pragma unroll
    for (int fm = 0; fm < 4; ++fm)
#pragma unroll
      for (int fn = 0; fn < 4; ++fn)
        acc[fm][fn] = __builtin_amdgcn_mfma_f32_16x16x32_f16(a[fm], b[fn], acc[fm][fn], 0, 0, 0);
    __syncthreads();
  }

  float bv[4];
#pragma unroll
  for (int fn = 0; fn < 4; ++fn)
    bv[fn] = BIAS ? bias[colbase + wc + fn * 16 + (l & 15)] : 0.f;

#pragma unroll
  for (int fm = 0; fm < 4; ++fm) {
#pragma unroll
    for (int r = 0; r < 4; ++r) {
      int row = rowbase + wr + fm * 16 + (l >> 4) * 4 + r;
      if (row >= N) continue;
      float dv = DSCALE ? dinv[row] : 1.f;
#pragma unroll
      for (int fn = 0; fn < 4; ++fn) {
        int col = colbase + wc + fn * 16 + (l & 15);
        float v = acc[fm][fn][r] + bv[fn];
        if (RELU) v = fmaxf(v, 0.f);
        C[(size_t)row * M + col] = (f16)(v * dv);
      }
    }
  }
}

// ---------------- fp32 GEMM for the tiny head (N=2048) ----------------
template <int K, bool RELU, bool HAS_BIAS>
__global__ __launch_bounds__(256) void gemm_k(const float* __restrict__ A,
                                              const float* __restrict__ W,
                                              const float* __restrict__ bias,
                                              float* __restrict__ C, int N, int M) {
  constexpr int KB = 16;
  __shared__ float As[KB][128];
  __shared__ float Ws[KB][128];

  const int tid = threadIdx.x;
  const int rowbase = blockIdx.x * 128;
  const int colbase = blockIdx.y * 128;
  const int tr = tid >> 4;
  const int tc = tid & 15;
  const int ar = tid >> 1;
  const int ac4_0 = (tid & 1) * 2;
  const int wk = tid >> 4;
  const int wc4_0 = (tid & 15) * 2;

  float acc[8][8];
#pragma unroll
  for (int i = 0; i < 8; ++i)
#pragma unroll
    for (int j = 0; j < 8; ++j) acc[i][j] = 0.f;

  for (int kb = 0; kb < K; kb += KB) {
#pragma unroll
    for (int q = 0; q < 2; ++q) {
      int c4 = ac4_0 + q;
      int grow = rowbase + ar;
      float4 v = make_float4(0.f, 0.f, 0.f, 0.f);
      if (grow < N) v = *(const float4*)(A + (size_t)grow * K + kb + c4 * 4);
      As[c4 * 4 + 0][ar] = v.x;
      As[c4 * 4 + 1][ar] = v.y;
      As[c4 * 4 + 2][ar] = v.z;
      As[c4 * 4 + 3][ar] = v.w;
    }
#pragma unroll
    for (int q = 0; q < 2; ++q) {
      int c4 = wc4_0 + q;
      float4 v = *(const float4*)(W + (size_t)(kb + wk) * M + colbase + c4 * 4);
      *(float4*)&Ws[wk][c4 * 4] = v;
    }
    __syncthreads();

#pragma unroll
    for (int kk = 0; kk < KB; ++kk) {
      float4 a0 = *(const float4*)&As[kk][tr * 4];
      float4 a1 = *(const float4*)&As[kk][tr * 4 + 64];
      float4 w0 = *(const float4*)&Ws[kk][tc * 4];
      float4 w1 = *(const float4*)&Ws[kk][tc * 4 + 64];
      float a[8] = {a0.x, a0.y, a0.z, a0.w, a1.x, a1.y, a1.z, a1.w};
      float w[8] = {w0.x, w0.y, w0.z, w0.w, w1.x, w1.y, w1.z, w1.w};
#pragma unroll
      for (int i = 0; i < 8; ++i)
#pragma unroll
        for (int j = 0; j < 8; ++j) acc[i][j] = fmaf(a[i], w[j], acc[i][j]);
    }
    __syncthreads();
  }

#pragma unroll
  for (int i = 0; i < 8; ++i) {
    int r = rowbase + ((i < 4) ? (tr * 4 + i) : (64 + tr * 4 + (i - 4)));
    if (r >= N) continue;
#pragma unroll
    for (int jh = 0; jh < 2; ++jh) {
      int c = colbase + tc * 4 + jh * 64;
      float4 o;
      o.x = acc[i][jh * 4 + 0];
      o.y = acc[i][jh * 4 + 1];
      o.z = acc[i][jh * 4 + 2];
      o.w = acc[i][jh * 4 + 3];
      if (HAS_BIAS) {
        o.x += bias[c]; o.y += bias[c + 1]; o.z += bias[c + 2]; o.w += bias[c + 3];
      }
      if (RELU) {
        o.x = fmaxf(o.x, 0.f); o.y = fmaxf(o.y, 0.f);
        o.z = fmaxf(o.z, 0.f); o.w = fmaxf(o.w, 0.f);
      }
      *(float4*)(C + (size_t)r * M + c) = o;
    }
  }
}

// ---------------- mean pooling per graph (batch sorted) ----------------
__global__ void pool_k(const float* __restrict__ h, const int* __restrict__ batch,
                       float* __restrict__ pooled) {
  int g = blockIdx.x;
  int j = threadIdx.x;  // 128 threads = EMBD
  int lo = 0, hi = NODES;
  while (lo < hi) { int mid = (lo + hi) >> 1; if (batch[mid] < g) lo = mid + 1; else hi = mid; }
  int start = lo;
  int lo2 = start, hi2 = NODES;
  while (lo2 < hi2) { int mid = (lo2 + hi2) >> 1; if (batch[mid] < g + 1) lo2 = mid + 1; else hi2 = mid; }
  int end = lo2;
  float s = 0.f;
  for (int r = start; r < end; ++r) s += h[(size_t)r * EMBD + j];
  float c = (float)(end - start);
  pooled[g * EMBD + j] = s / fmaxf(c, 1.f);
}

// ---------------- head: logits = z2 @ Wc3[128,2] + bc3 ----------------
__global__ void head_k(const float* __restrict__ z2, const float* __restrict__ Wc3,
                       const float* __restrict__ bc3, float* __restrict__ out) {
  int wv = (blockIdx.x * blockDim.x + threadIdx.x) >> 6;
  int lane = threadIdx.x & 63;
  if (wv >= GRAPHS) return;
  float2 z = *(const float2*)(z2 + (size_t)wv * 128 + lane * 2);
  int j0 = lane * 2;
  float a0 = z.x * Wc3[j0 * 2 + 0] + z.y * Wc3[(j0 + 1) * 2 + 0];
  float a1 = z.x * Wc3[j0 * 2 + 1] + z.y * Wc3[(j0 + 1) * 2 + 1];
  for (int off = 32; off; off >>= 1) {
    a0 += __shfl_down(a0, off);
    a1 += __shfl_down(a1, off);
  }
  if (lane == 0) {
    out[wv * 2 + 0] = a0 + bc3[0];
    out[wv * 2 + 1] = a1 + bc3[1];
  }
}

extern "C" void kernel_launch(void* const* d_in, const int* in_sizes, int n_in,
                              void* d_out, int out_size, void* d_ws, size_t ws_size,
                              hipStream_t stream) {
  const float* x    = (const float*)d_in[0];
  const int*   ei   = (const int*)d_in[1];
  const int*   batch= (const int*)d_in[2];
  const float* W1 = (const float*)d_in[3];  const float* b1 = (const float*)d_in[4];
  const float* W2 = (const float*)d_in[5];  const float* b2 = (const float*)d_in[6];
  const float* W3 = (const float*)d_in[7];  const float* b3 = (const float*)d_in[8];
  const float* Wc1= (const float*)d_in[9];  const float* bc1= (const float*)d_in[10];
  const float* Wc2= (const float*)d_in[11]; const float* bc2= (const float*)d_in[12];
  const float* Wc3= (const float*)d_in[13]; const float* bc3= (const float*)d_in[14];
  float* out = (float*)d_out;

  char* ws = (char*)d_ws;
  size_t off = 0;
  auto alloc = [&](size_t bytes) -> void* {
    void* p = ws + off;
    off = (off + bytes + 255) & ~(size_t)255;
    return p;
  };
  f16*   F0      = (f16*)alloc((size_t)NODES * 256 * 2);
  f16*   F1      = (f16*)alloc((size_t)NODES * 256 * 2);
  float* R0      = (float*)alloc((size_t)NODES * 128 * 4);
  int*   csr_src = (int*)alloc((size_t)EDGES * 4);
  int*   row_ptr = (int*)alloc((size_t)(NODES + 1) * 4);
  int*   cnt     = (int*)alloc((size_t)NODES * 4);
  int*   cursor  = (int*)alloc((size_t)NODES * 4);
  float* dinv    = (float*)alloc((size_t)NODES * 4);
  int*   bsum    = (int*)alloc(512 * 4);
  f16*   Wt1     = (f16*)alloc((size_t)FIN * HIDDEN * 2);
  f16*   Wt2     = (f16*)alloc((size_t)HIDDEN * HIDDEN * 2);
  f16*   Wt3     = (f16*)alloc((size_t)HIDDEN * EMBD * 2);
  // fp32 overlays in F0 (dead after GEMM3 consumed it -> reused post-agg3)
  float* pooled = (float*)F0;
  float* z1     = pooled + (size_t)GRAPHS * EMBD;
  float* z2     = z1 + (size_t)GRAPHS * HIDDEN;

  const int* srcA = ei;
  const int* dstA = ei + EDGES;

  const int nb = (NODES + 255) / 256;  // 391
  hipMemsetAsync(cnt, 0, (size_t)NODES * 4, stream);
  hist_k<<<2048, 256, 0, stream>>>(dstA, cnt);
  scan1_k<<<nb, 256, 0, stream>>>(cnt, row_ptr, bsum);
  scan2_k<<<1, 512, 0, stream>>>(bsum, nb);
  scan3_k<<<nb, 256, 0, stream>>>(cnt, bsum, row_ptr, dinv, cursor);
  fill_k<<<2048, 256, 0, stream>>>(srcA, dstA, row_ptr, cursor, csr_src);

  convw_k<<<(FIN * HIDDEN + 255) / 256, 256, 0, stream>>>(W1, Wt1, FIN, HIDDEN);
  convw_k<<<(HIDDEN * HIDDEN + 255) / 256, 256, 0, stream>>>(W2, Wt2, HIDDEN, HIDDEN);
  convw_k<<<(HIDDEN * EMBD + 255) / 256, 256, 0, stream>>>(W3, Wt3, HIDDEN, EMBD);
  prescale_k<<<(NODES * FIN / 4 + 255) / 256, 256, 0, stream>>>(x, dinv, F0);

  const int aggBlocks = (NODES * 64 + 255) / 256;  // 25000
  const int gemmRows = (NODES + 127) / 128;        // 782

  // L1: AX = dinv*(sum xs) [128 f16]; H1s = dinv*relu(AX@W1+b1) [256 f16]
  agg_h<2, false><<<aggBlocks, 256, 0, stream>>>(F0, F1, row_ptr, csr_src, dinv, nullptr);
  gemm_h<FIN, true, true, true><<<dim3(gemmRows, 2), 256, 0, stream>>>(F1, Wt1, b1, dinv, F0, NODES, HIDDEN);
  // L2: AH1 = dinv*(sum H1s) [256 f16]; H2s = dinv*relu(AH1@W2+b2) [256 f16]
  agg_h<4, false><<<aggBlocks, 256, 0, stream>>>(F0, F1, row_ptr, csr_src, dinv, nullptr);
  gemm_h<HIDDEN, true, true, true><<<dim3(gemmRows, 2), 256, 0, stream>>>(F1, Wt2, b2, dinv, F0, NODES, HIDDEN);
  // L3: G3s = H2s@W3 [128 f16] (prescale carried through); H3 = dinv*(sum G3s)+b3 [128 f32]
  gemm_h<HIDDEN, false, false, false><<<dim3(gemmRows, 1), 256, 0, stream>>>(F0, Wt3, nullptr, nullptr, F1, NODES, EMBD);
  agg_h<2, true><<<aggBlocks, 256, 0, stream>>>(F1, R0, row_ptr, csr_src, dinv, b3);

  // pooling + MLP head (fp32)
  pool_k<<<GRAPHS, 128, 0, stream>>>(R0, batch, pooled);
  gemm_k<EMBD, true, true><<<dim3((GRAPHS + 127) / 128, 2), 256, 0, stream>>>(pooled, Wc1, bc1, z1, GRAPHS, HIDDEN);
  gemm_k<HIDDEN, true, true><<<dim3((GRAPHS + 127) / 128, 1), 256, 0, stream>>>(z1, Wc2, bc2, z2, GRAPHS, EMBD);
  head_k<<<GRAPHS / 4, 256, 0, stream>>>(z2, Wc3, bc3, out);
}

// Round 3
// 984.049 us; speedup vs baseline: 1.8976x; 1.4209x over previous
//
#include <hip/hip_runtime.h>
#include <cstdint>
#include <cstddef>

#define NODES  100000
#define EDGES  3200000
#define FIN    128
#define HIDDEN 256
#define EMBD   128
#define GRAPHS 2048

typedef _Float16 f16;
typedef f16 f16x2 __attribute__((ext_vector_type(2)));
typedef f16 f16x4 __attribute__((ext_vector_type(4)));
typedef f16 f16x8 __attribute__((ext_vector_type(8)));
typedef float f32x4 __attribute__((ext_vector_type(4)));

// ---------------- CSR build ----------------
__global__ void hist_k(const int* __restrict__ dst, int* __restrict__ cnt) {
  int stride = gridDim.x * blockDim.x;
  for (int i = blockIdx.x * blockDim.x + threadIdx.x; i < EDGES; i += stride)
    atomicAdd(&cnt[dst[i]], 1);
}

__global__ void scan1_k(const int* __restrict__ cnt, int* __restrict__ row_ptr,
                        int* __restrict__ bsum) {
  __shared__ int sh[256];
  int i = blockIdx.x * 256 + threadIdx.x;
  int v = (i < NODES) ? cnt[i] : 0;
  sh[threadIdx.x] = v;
  __syncthreads();
  for (int off = 1; off < 256; off <<= 1) {
    int t = (threadIdx.x >= off) ? sh[threadIdx.x - off] : 0;
    __syncthreads();
    sh[threadIdx.x] += t;
    __syncthreads();
  }
  if (i < NODES) row_ptr[i + 1] = sh[threadIdx.x];
  if (threadIdx.x == 255) bsum[blockIdx.x] = sh[255];
}

__global__ void scan2_k(int* __restrict__ bsum, int nb) {
  __shared__ int sh[512];
  int v = (threadIdx.x < nb) ? bsum[threadIdx.x] : 0;
  sh[threadIdx.x] = v;
  __syncthreads();
  for (int off = 1; off < 512; off <<= 1) {
    int t = (threadIdx.x >= off) ? sh[threadIdx.x - off] : 0;
    __syncthreads();
    sh[threadIdx.x] += t;
    __syncthreads();
  }
  if (threadIdx.x < nb) bsum[threadIdx.x] = sh[threadIdx.x] - v;  // exclusive
}

__global__ void scan3_k(const int* __restrict__ cnt, const int* __restrict__ bsum,
                        int* __restrict__ row_ptr, float* __restrict__ dinv,
                        int* __restrict__ cursor) {
  int i = blockIdx.x * 256 + threadIdx.x;
  if (i >= NODES) return;
  row_ptr[i + 1] += bsum[blockIdx.x];
  dinv[i] = rsqrtf((float)(cnt[i] + 1));
  cursor[i] = 0;
  if (i == 0) row_ptr[0] = 0;
}

__global__ void fill_k(const int* __restrict__ src, const int* __restrict__ dst,
                       const int* __restrict__ row_ptr, int* __restrict__ cursor,
                       int* __restrict__ csr_src) {
  int stride = gridDim.x * blockDim.x;
  for (int i = blockIdx.x * blockDim.x + threadIdx.x; i < EDGES; i += stride) {
    int d = dst[i];
    int pos = row_ptr[d] + atomicAdd(&cursor[d], 1);
    csr_src[pos] = src[i];
  }
}

// ---------------- prescale: xs[i] = f16(dinv[i] * x[i]) ----------------
__global__ void prescale_k(const float* __restrict__ x, const float* __restrict__ dinv,
                           f16* __restrict__ xs) {
  int idx = blockIdx.x * blockDim.x + threadIdx.x;  // over NODES*FIN/4
  if (idx >= NODES * FIN / 4) return;
  int row = idx >> 5;  // FIN/4 = 32 float4 per row
  float4 v = *(const float4*)(x + (size_t)idx * 4);
  float d = dinv[row];
  f16x4 o = {(f16)(d * v.x), (f16)(d * v.y), (f16)(d * v.z), (f16)(d * v.w)};
  *(f16x4*)(xs + (size_t)idx * 4) = o;
}

// ---------------- weight convert+transpose: Wt[m][k] = f16(W[k][m]) ----------------
__global__ void convw_k(const float* __restrict__ W, f16* __restrict__ Wt, int K, int M) {
  int i = blockIdx.x * blockDim.x + threadIdx.x;
  if (i >= K * M) return;
  int k = i / M, m = i - k * M;
  Wt[(size_t)m * K + k] = (f16)W[i];
}

// ---------------- aggregation (f16 in, fp32 accum), 8-deep MLP unroll ----------------
// in is dinv-prescaled: out[i] = dinv[i] * (sum_{s in N(i)} in[s] + in[i]) (+bias, FINAL->fp32)
template <int V, bool FINAL>
__global__ __launch_bounds__(256) void agg_h(const f16* __restrict__ in, void* __restrict__ outv,
                      const int* __restrict__ row_ptr, const int* __restrict__ csr_src,
                      const float* __restrict__ dinv, const float* __restrict__ bias) {
  constexpr int D = V * 64;
  constexpr int U = 8;  // gathers kept in flight
  int node = (blockIdx.x * blockDim.x + threadIdx.x) >> 6;
  int lane = threadIdx.x & 63;
  if (node >= NODES) return;
  const int c0 = lane * V;
  const f16* __restrict__ inc = in + c0;

  float acc[V];
#pragma unroll
  for (int v = 0; v < V; ++v) acc[v] = 0.f;

  int beg = row_ptr[node], end = row_ptr[node + 1];
  int k = beg;
  for (; k + U <= end; k += U) {
    int s[U];
#pragma unroll
    for (int u = 0; u < U; ++u) s[u] = csr_src[k + u];
    if (V == 4) {
      f16x4 hv[U];
#pragma unroll
      for (int u = 0; u < U; ++u) hv[u] = *(const f16x4*)(inc + (size_t)s[u] * D);
#pragma unroll
      for (int u = 0; u < U; ++u) {
        acc[0] += (float)hv[u][0]; acc[1] += (float)hv[u][1];
        acc[2] += (float)hv[u][2]; acc[3] += (float)hv[u][3];
      }
    } else {
      f16x2 hv[U];
#pragma unroll
      for (int u = 0; u < U; ++u) hv[u] = *(const f16x2*)(inc + (size_t)s[u] * D);
#pragma unroll
      for (int u = 0; u < U; ++u) {
        acc[0] += (float)hv[u][0]; acc[1] += (float)hv[u][1];
      }
    }
  }
  // tail (includes self-loop as one extra "edge")
  for (; k < end; ++k) {
    int s = csr_src[k];
    if (V == 4) {
      f16x4 hv = *(const f16x4*)(inc + (size_t)s * D);
      acc[0] += (float)hv[0]; acc[1] += (float)hv[1];
      acc[2] += (float)hv[2]; acc[3] += (float)hv[3];
    } else {
      f16x2 hv = *(const f16x2*)(inc + (size_t)s * D);
      acc[0] += (float)hv[0]; acc[1] += (float)hv[1];
    }
  }
  // self-loop term
  if (V == 4) {
    f16x4 hv = *(const f16x4*)(inc + (size_t)node * D);
    acc[0] += (float)hv[0]; acc[1] += (float)hv[1];
    acc[2] += (float)hv[2]; acc[3] += (float)hv[3];
  } else {
    f16x2 hv = *(const f16x2*)(inc + (size_t)node * D);
    acc[0] += (float)hv[0]; acc[1] += (float)hv[1];
  }

  float di = dinv[node];
  if (FINAL) {
    float* out = (float*)outv;
    if (V == 4) {
      float4 o = {di * acc[0] + bias[c0], di * acc[1] + bias[c0 + 1],
                  di * acc[2] + bias[c0 + 2], di * acc[3] + bias[c0 + 3]};
      *(float4*)(out + (size_t)node * D + c0) = o;
    } else {
      float2 o = {di * acc[0] + bias[c0], di * acc[1] + bias[c0 + 1]};
      *(float2*)(out + (size_t)node * D + c0) = o;
    }
  } else {
    f16* out = (f16*)outv;
    if (V == 4) {
      f16x4 o = {(f16)(di * acc[0]), (f16)(di * acc[1]),
                 (f16)(di * acc[2]), (f16)(di * acc[3])};
      *(f16x4*)(out + (size_t)node * D + c0) = o;
    } else {
      f16x2 o = {(f16)(di * acc[0]), (f16)(di * acc[1])};
      *(f16x2*)(out + (size_t)node * D + c0) = o;
    }
  }
}

// ---------------- f16 MFMA GEMM: C[N,M] = epi(A[N,K] @ W[K,M]) ----------------
template <int K, bool RELU, bool BIAS, bool DSCALE>
__global__ __launch_bounds__(256) void gemm_h(const f16* __restrict__ A,
                                              const f16* __restrict__ Wt,
                                              const float* __restrict__ bias,
                                              const float* __restrict__ dinv,
                                              f16* __restrict__ C, int N, int M) {
  __shared__ f16 As[128][40];  // [row][k], pad to 40 halves (80B) for bank spread
  __shared__ f16 Bs[128][40];  // [col][k]

  const int tid = threadIdx.x;
  const int rowbase = blockIdx.x * 128;
  const int colbase = blockIdx.y * 128;
  const int l = tid & 63;
  const int wr = ((tid >> 6) >> 1) * 64;  // wave row offset 0/64
  const int wc = ((tid >> 6) & 1) * 64;   // wave col offset 0/64
  const int lr = tid >> 1;                // 0..127: tile row (A) / tile col (B)
  const int lc = (tid & 1) * 16;          // half-offset within BK=32

  f32x4 acc[4][4];
#pragma unroll
  for (int i = 0; i < 4; ++i)
#pragma unroll
    for (int j = 0; j < 4; ++j) acc[i][j] = (f32x4){0.f, 0.f, 0.f, 0.f};

  const int arow = min(rowbase + lr, N - 1);  // clamp: OOB rows read row N-1, never stored
  const f16* aptr = A + (size_t)arow * K + lc;
  const f16* bptr = Wt + (size_t)(colbase + lr) * K + lc;

  for (int kb = 0; kb < K; kb += 32) {
    *(f16x8*)&As[lr][lc]     = *(const f16x8*)(aptr + kb);
    *(f16x8*)&As[lr][lc + 8] = *(const f16x8*)(aptr + kb + 8);
    *(f16x8*)&Bs[lr][lc]     = *(const f16x8*)(bptr + kb);
    *(f16x8*)&Bs[lr][lc + 8] = *(const f16x8*)(bptr + kb + 8);
    __syncthreads();

    f16x8 a[4], b[4];
#pragma unroll
    for (int f = 0; f < 4; ++f) {
      a[f] = *(const f16x8*)&As[wr + f * 16 + (l & 15)][(l >> 4) * 8];
      b[f] = *(const f16x8*)&Bs[wc + f * 16 + (l & 15)][(l >> 4) * 8];
    }
#pragma unroll
    for (int fm = 0; fm < 4; ++fm)
#pragma unroll
      for (int fn = 0; fn < 4; ++fn)
        acc[fm][fn] = __builtin_amdgcn_mfma_f32_16x16x32_f16(a[fm], b[fn], acc[fm][fn], 0, 0, 0);
    __syncthreads();
  }

  float bv[4];
#pragma unroll
  for (int fn = 0; fn < 4; ++fn)
    bv[fn] = BIAS ? bias[colbase + wc + fn * 16 + (l & 15)] : 0.f;

#pragma unroll
  for (int fm = 0; fm < 4; ++fm) {
#pragma unroll
    for (int r = 0; r < 4; ++r) {
      int row = rowbase + wr + fm * 16 + (l >> 4) * 4 + r;
      if (row >= N) continue;
      float dv = DSCALE ? dinv[row] : 1.f;
#pragma unroll
      for (int fn = 0; fn < 4; ++fn) {
        int col = colbase + wc + fn * 16 + (l & 15);
        float v = acc[fm][fn][r] + bv[fn];
        if (RELU) v = fmaxf(v, 0.f);
        C[(size_t)row * M + col] = (f16)(v * dv);
      }
    }
  }
}

// ---------------- fp32 GEMM for the tiny head (N=2048) ----------------
template <int K, bool RELU, bool HAS_BIAS>
__global__ __launch_bounds__(256) void gemm_k(const float* __restrict__ A,
                                              const float* __restrict__ W,
                                              const float* __restrict__ bias,
                                              float* __restrict__ C, int N, int M) {
  constexpr int KB = 16;
  __shared__ float As[KB][128];
  __shared__ float Ws[KB][128];

  const int tid = threadIdx.x;
  const int rowbase = blockIdx.x * 128;
  const int colbase = blockIdx.y * 128;
  const int tr = tid >> 4;
  const int tc = tid & 15;
  const int ar = tid >> 1;
  const int ac4_0 = (tid & 1) * 2;
  const int wk = tid >> 4;
  const int wc4_0 = (tid & 15) * 2;

  float acc[8][8];
#pragma unroll
  for (int i = 0; i < 8; ++i)
#pragma unroll
    for (int j = 0; j < 8; ++j) acc[i][j] = 0.f;

  for (int kb = 0; kb < K; kb += KB) {
#pragma unroll
    for (int q = 0; q < 2; ++q) {
      int c4 = ac4_0 + q;
      int grow = rowbase + ar;
      float4 v = make_float4(0.f, 0.f, 0.f, 0.f);
      if (grow < N) v = *(const float4*)(A + (size_t)grow * K + kb + c4 * 4);
      As[c4 * 4 + 0][ar] = v.x;
      As[c4 * 4 + 1][ar] = v.y;
      As[c4 * 4 + 2][ar] = v.z;
      As[c4 * 4 + 3][ar] = v.w;
    }
#pragma unroll
    for (int q = 0; q < 2; ++q) {
      int c4 = wc4_0 + q;
      float4 v = *(const float4*)(W + (size_t)(kb + wk) * M + colbase + c4 * 4);
      *(float4*)&Ws[wk][c4 * 4] = v;
    }
    __syncthreads();

#pragma unroll
    for (int kk = 0; kk < KB; ++kk) {
      float4 a0 = *(const float4*)&As[kk][tr * 4];
      float4 a1 = *(const float4*)&As[kk][tr * 4 + 64];
      float4 w0 = *(const float4*)&Ws[kk][tc * 4];
      float4 w1 = *(const float4*)&Ws[kk][tc * 4 + 64];
      float a[8] = {a0.x, a0.y, a0.z, a0.w, a1.x, a1.y, a1.z, a1.w};
      float w[8] = {w0.x, w0.y, w0.z, w0.w, w1.x, w1.y, w1.z, w1.w};
#pragma unroll
      for (int i = 0; i < 8; ++i)
#pragma unroll
        for (int j = 0; j < 8; ++j) acc[i][j] = fmaf(a[i], w[j], acc[i][j]);
    }
    __syncthreads();
  }

#pragma unroll
  for (int i = 0; i < 8; ++i) {
    int r = rowbase + ((i < 4) ? (tr * 4 + i) : (64 + tr * 4 + (i - 4)));
    if (r >= N) continue;
#pragma unroll
    for (int jh = 0; jh < 2; ++jh) {
      int c = colbase + tc * 4 + jh * 64;
      float4 o;
      o.x = acc[i][jh * 4 + 0];
      o.y = acc[i][jh * 4 + 1];
      o.z = acc[i][jh * 4 + 2];
      o.w = acc[i][jh * 4 + 3];
      if (HAS_BIAS) {
        o.x += bias[c]; o.y += bias[c + 1]; o.z += bias[c + 2]; o.w += bias[c + 3];
      }
      if (RELU) {
        o.x = fmaxf(o.x, 0.f); o.y = fmaxf(o.y, 0.f);
        o.z = fmaxf(o.z, 0.f); o.w = fmaxf(o.w, 0.f);
      }
      *(float4*)(C + (size_t)r * M + c) = o;
    }
  }
}

// ---------------- mean pooling per graph (batch sorted) ----------------
__global__ void pool_k(const float* __restrict__ h, const int* __restrict__ batch,
                       float* __restrict__ pooled) {
  int g = blockIdx.x;
  int j = threadIdx.x;  // 128 threads = EMBD
  int lo = 0, hi = NODES;
  while (lo < hi) { int mid = (lo + hi) >> 1; if (batch[mid] < g) lo = mid + 1; else hi = mid; }
  int start = lo;
  int lo2 = start, hi2 = NODES;
  while (lo2 < hi2) { int mid = (lo2 + hi2) >> 1; if (batch[mid] < g + 1) lo2 = mid + 1; else hi2 = mid; }
  int end = lo2;
  float s = 0.f;
  for (int r = start; r < end; ++r) s += h[(size_t)r * EMBD + j];
  float c = (float)(end - start);
  pooled[g * EMBD + j] = s / fmaxf(c, 1.f);
}

// ---------------- head: logits = z2 @ Wc3[128,2] + bc3 ----------------
__global__ void head_k(const float* __restrict__ z2, const float* __restrict__ Wc3,
                       const float* __restrict__ bc3, float* __restrict__ out) {
  int wv = (blockIdx.x * blockDim.x + threadIdx.x) >> 6;
  int lane = threadIdx.x & 63;
  if (wv >= GRAPHS) return;
  float2 z = *(const float2*)(z2 + (size_t)wv * 128 + lane * 2);
  int j0 = lane * 2;
  float a0 = z.x * Wc3[j0 * 2 + 0] + z.y * Wc3[(j0 + 1) * 2 + 0];
  float a1 = z.x * Wc3[j0 * 2 + 1] + z.y * Wc3[(j0 + 1) * 2 + 1];
  for (int off = 32; off; off >>= 1) {
    a0 += __shfl_down(a0, off);
    a1 += __shfl_down(a1, off);
  }
  if (lane == 0) {
    out[wv * 2 + 0] = a0 + bc3[0];
    out[wv * 2 + 1] = a1 + bc3[1];
  }
}

extern "C" void kernel_launch(void* const* d_in, const int* in_sizes, int n_in,
                              void* d_out, int out_size, void* d_ws, size_t ws_size,
                              hipStream_t stream) {
  const float* x    = (const float*)d_in[0];
  const int*   ei   = (const int*)d_in[1];
  const int*   batch= (const int*)d_in[2];
  const float* W1 = (const float*)d_in[3];  const float* b1 = (const float*)d_in[4];
  const float* W2 = (const float*)d_in[5];  const float* b2 = (const float*)d_in[6];
  const float* W3 = (const float*)d_in[7];  const float* b3 = (const float*)d_in[8];
  const float* Wc1= (const float*)d_in[9];  const float* bc1= (const float*)d_in[10];
  const float* Wc2= (const float*)d_in[11]; const float* bc2= (const float*)d_in[12];
  const float* Wc3= (const float*)d_in[13]; const float* bc3= (const float*)d_in[14];
  float* out = (float*)d_out;

  char* ws = (char*)d_ws;
  size_t off = 0;
  auto alloc = [&](size_t bytes) -> void* {
    void* p = ws + off;
    off = (off + bytes + 255) & ~(size_t)255;
    return p;
  };
  f16*   F0      = (f16*)alloc((size_t)NODES * 256 * 2);
  f16*   F1      = (f16*)alloc((size_t)NODES * 256 * 2);
  float* R0      = (float*)alloc((size_t)NODES * 128 * 4);
  int*   csr_src = (int*)alloc((size_t)EDGES * 4);
  int*   row_ptr = (int*)alloc((size_t)(NODES + 1) * 4);
  int*   cnt     = (int*)alloc((size_t)NODES * 4);
  int*   cursor  = (int*)alloc((size_t)NODES * 4);
  float* dinv    = (float*)alloc((size_t)NODES * 4);
  int*   bsum    = (int*)alloc(512 * 4);
  f16*   Wt1     = (f16*)alloc((size_t)FIN * HIDDEN * 2);
  f16*   Wt2     = (f16*)alloc((size_t)HIDDEN * HIDDEN * 2);
  f16*   Wt3     = (f16*)alloc((size_t)HIDDEN * EMBD * 2);
  // fp32 overlays in F0 (dead after GEMM3 consumed it -> reused post-agg3)
  float* pooled = (float*)F0;
  float* z1     = pooled + (size_t)GRAPHS * EMBD;
  float* z2     = z1 + (size_t)GRAPHS * HIDDEN;

  const int* srcA = ei;
  const int* dstA = ei + EDGES;

  const int nb = (NODES + 255) / 256;  // 391
  hipMemsetAsync(cnt, 0, (size_t)NODES * 4, stream);
  hist_k<<<2048, 256, 0, stream>>>(dstA, cnt);
  scan1_k<<<nb, 256, 0, stream>>>(cnt, row_ptr, bsum);
  scan2_k<<<1, 512, 0, stream>>>(bsum, nb);
  scan3_k<<<nb, 256, 0, stream>>>(cnt, bsum, row_ptr, dinv, cursor);
  fill_k<<<2048, 256, 0, stream>>>(srcA, dstA, row_ptr, cursor, csr_src);

  convw_k<<<(FIN * HIDDEN + 255) / 256, 256, 0, stream>>>(W1, Wt1, FIN, HIDDEN);
  convw_k<<<(HIDDEN * HIDDEN + 255) / 256, 256, 0, stream>>>(W2, Wt2, HIDDEN, HIDDEN);
  convw_k<<<(HIDDEN * EMBD + 255) / 256, 256, 0, stream>>>(W3, Wt3, HIDDEN, EMBD);
  prescale_k<<<(NODES * FIN / 4 + 255) / 256, 256, 0, stream>>>(x, dinv, F0);

  const int aggBlocks = (NODES * 64 + 255) / 256;  // 25000
  const int gemmRows = (NODES + 127) / 128;        // 782

  // L1: AX = dinv*(sum xs) [128 f16]; H1s = dinv*relu(AX@W1+b1) [256 f16]
  agg_h<2, false><<<aggBlocks, 256, 0, stream>>>(F0, F1, row_ptr, csr_src, dinv, nullptr);
  gemm_h<FIN, true, true, true><<<dim3(gemmRows, 2), 256, 0, stream>>>(F1, Wt1, b1, dinv, F0, NODES, HIDDEN);
  // L2: AH1 = dinv*(sum H1s) [256 f16]; H2s = dinv*relu(AH1@W2+b2) [256 f16]
  agg_h<4, false><<<aggBlocks, 256, 0, stream>>>(F0, F1, row_ptr, csr_src, dinv, nullptr);
  gemm_h<HIDDEN, true, true, true><<<dim3(gemmRows, 2), 256, 0, stream>>>(F1, Wt2, b2, dinv, F0, NODES, HIDDEN);
  // L3: G3s = H2s@W3 [128 f16] (prescale carried through); H3 = dinv*(sum G3s)+b3 [128 f32]
  gemm_h<HIDDEN, false, false, false><<<dim3(gemmRows, 1), 256, 0, stream>>>(F0, Wt3, nullptr, nullptr, F1, NODES, EMBD);
  agg_h<2, true><<<aggBlocks, 256, 0, stream>>>(F1, R0, row_ptr, csr_src, dinv, b3);

  // pooling + MLP head (fp32)
  pool_k<<<GRAPHS, 128, 0, stream>>>(R0, batch, pooled);
  gemm_k<EMBD, true, true><<<dim3((GRAPHS + 127) / 128, 2), 256, 0, stream>>>(pooled, Wc1, bc1, z1, GRAPHS, HIDDEN);
  gemm_k<HIDDEN, true, true><<<dim3((GRAPHS + 127) / 128, 1), 256, 0, stream>>>(z1, Wc2, bc2, z2, GRAPHS, EMBD);
  head_k<<<GRAPHS / 4, 256, 0, stream>>>(z2, Wc3, bc3, out);
}